// Round 3
// baseline (231.824 us; speedup 1.0000x reference)
//
#include <hip/hip_runtime.h>

// DilateAttention: B=4, d=384 (12 heads x 32), H=W=64, 3x3 taps, dilation 2, pad 2.
// f32 in / f32 out.
// v4: v1's clean-traffic geometry (multi-row blocks, NO xcd swizzle, per-lane
// contiguous output ownership) + 2-way in-wave channel split for concurrency.
//   - 16 ch/lane, hg = lane bit 5 -> QK cross-group reduce = one shfl_xor(32).
//   - 6144 waves (2x v1), ~halved per-wave load chain, only 2x setup redundancy
//     (v2/v3's 4-way split cost 8x VALU-cycles and regressed).
//   - v2/v3's WRITE_SIZE blowup (147 MB vs 25 MB output) persisted even with
//     dense LDS-transposed stores => store-instruction shape exonerated;
//     suspect = xcd swizzle / row-block geometry. Both reverted here.

#define NHD  12
#define DDIM 384
#define HH   64
#define WW   64
#define HWSZ 4096
#define SCALEF 0.17677669529663687f  // 1/sqrt(32)

// block = 256 = 4 waves; wave = 32 pixels x 2 half-channel groups (hg=bit5).
// block covers 2 rows x 64 x. grid = B*NH*(H/2) = 1536. 6 blocks/CU resident.
__global__ __launch_bounds__(256, 6) void dilate_attn(const float* __restrict__ q,
                                                      const float* __restrict__ k,
                                                      const float* __restrict__ v,
                                                      float* __restrict__ out) {
    const int tid = threadIdx.x;
    const int xi  = tid & 31;            // x within half-row
    const int hg  = (tid >> 5) & 1;      // half-channel group (16 ch each), lane bit 5
    const int xh  = (tid >> 6) & 1;      // which half-row of x
    const int r   = tid >> 7;            // 0..1 row within block
    const int x   = xh * 32 + xi;

    const int bz = blockIdx.x;           // no swizzle: default round-robin XCD map
    const int bh = bz >> 5;              // b*NH + n
    const int y  = (bz & 31) * 2 + r;
    const int b  = bh / NHD;
    const int n  = bh - b * NHD;

    // 32-bit element indexing throughout.
    const int cbase = (b * DDIM + n * 32 + hg * 16) * HWSZ;
    const int pix   = y * WW + x;

    // 9 tap offsets, clamped to center when OOB; validity recorded separately.
    int  toff[9];
    bool tval[9];
#pragma unroll
    for (int di = 0; di < 3; ++di) {
        int yy = y + 2 * di - 2;
        bool vy = (yy >= 0) && (yy < HH);
#pragma unroll
        for (int p = 0; p < 3; ++p) {
            int xo = x + 2 * p - 2;
            bool ok = vy && (xo >= 0) && (xo < WW);
            tval[di * 3 + p] = ok;
            toff[di * 3 + p] = ok ? (yy * WW + xo) : pix;  // clamped: in-bounds
        }
    }

    // ---------------- preload q (scale folded in): 16 channels ---------------
    float qreg[16];
#pragma unroll
    for (int c = 0; c < 16; ++c) qreg[c] = q[cbase + pix + c * HWSZ] * SCALEF;

    // ---------------- Phase 1: 9 partial logits over 16 channels -------------
    float l[9];
#pragma unroll
    for (int t = 0; t < 9; ++t) {
        const int kb = cbase + toff[t];
        float a0 = 0.f, a1 = 0.f;
#pragma unroll
        for (int c = 0; c < 16; c += 2) {
            a0 += qreg[c]     * k[kb + c * HWSZ];
            a1 += qreg[c + 1] * k[kb + (c + 1) * HWSZ];
        }
        l[t] = tval[t] ? (a0 + a1) : 0.f;  // zero-pad taps contribute logit 0
    }

    // ---- reduce across the 2 half-channel groups (lane bit 5) --------------
#pragma unroll
    for (int t = 0; t < 9; ++t) l[t] += __shfl_xor(l[t], 32, 64);

    // ---------------- Softmax over 9 (redundant in each hg, cheap) ----------
    float m = l[0];
#pragma unroll
    for (int t = 1; t < 9; ++t) m = fmaxf(m, l[t]);
    float w[9], s = 0.f;
#pragma unroll
    for (int t = 0; t < 9; ++t) { w[t] = __expf(l[t] - m); s += w[t]; }
    float inv = 1.0f / s;
#pragma unroll
    for (int t = 0; t < 9; ++t) w[t] = tval[t] ? (w[t] * inv) : 0.f;  // padded V == 0

    // ---------------- Phase 2: weighted V over this group's 16 channels -----
    float o[16];
#pragma unroll
    for (int c = 0; c < 16; ++c) o[c] = 0.f;
#pragma unroll
    for (int t = 0; t < 9; ++t) {
        const int vb = cbase + toff[t];
        float wt = w[t];
#pragma unroll
        for (int c = 0; c < 16; ++c) o[c] += wt * v[vb + c * HWSZ];
    }

    // ---------------- Output: lane owns 64 contiguous bytes -----------------
    // out[b, y, x, n*32 + hg*16 .. +16): 64-B aligned, four float4 stores.
    const int ob = pix * DDIM + b * (HH * WW * DDIM) + n * 32 + hg * 16;
#pragma unroll
    for (int j = 0; j < 4; ++j)
        *(float4*)(out + ob + j * 4) =
            make_float4(o[j * 4], o[j * 4 + 1], o[j * 4 + 2], o[j * 4 + 3]);
}

extern "C" void kernel_launch(void* const* d_in, const int* in_sizes, int n_in,
                              void* d_out, int out_size, void* d_ws, size_t ws_size,
                              hipStream_t stream) {
    const float* q = (const float*)d_in[0];
    const float* k = (const float*)d_in[1];
    const float* v = (const float*)d_in[2];
    float* out = (float*)d_out;
    hipLaunchKernelGGL(dilate_attn, dim3(1536), dim3(256), 0, stream, q, k, v, out);
}